// Round 2
// baseline (918.379 us; speedup 1.0000x reference)
//
#include <hip/hip_runtime.h>
#include <stdint.h>

// ScoreMatching: B=2048, D=64, H=512.
// out[b] = 0.5*||s_b||^2 + tr(W4 M3 W3 M2 W2 M1 W1)_b
// div_b = sum_{i,d} m2[i] * C[i,d] * G[i,d]
//   C = W2 @ (M1 .* W1)      [512 x 64]
//   G = W3^T @ (M3 .* W4^T)  [512 x 64]
// Forward in fp32 (precision for ||s||^2), coalesced via transposed weights.
// Divergence in bf16 MFMA.

typedef __attribute__((ext_vector_type(8))) short short8;
typedef __attribute__((ext_vector_type(4))) float f32x4;

__device__ __forceinline__ uint16_t f2bf(float f) {
  uint32_t u = __float_as_uint(f);
  uint32_t lsb = (u >> 16) & 1u;
  u += 0x7FFFu + lsb;  // round-to-nearest-even
  return (uint16_t)(u >> 16);
}

// ---------------- convert: bf16 copies/transposes + fp32 transposes ----------------
// W2bf  [512][512] = W2                    (bf16, div A-operand)
// W3Tbf [512][512] = W3^T                  (bf16, div A-operand)
// W1Tbf [64][512]  = W1^T                  (bf16, div B-operand)
// W4bf  [64][512]  = W4                    (bf16, div B-operand)
// W2Tf  [512][512] = W2^T                  (fp32, forward coalesced)
// W3Tf  [512][512] = W3^T                  (fp32)
// W1Tf  [64][512]  = W1^T                  (fp32)
// W4Tf  [512][64]  = W4^T                  (fp32)
__global__ __launch_bounds__(256) void convert_kernel(
    const float* __restrict__ W1, const float* __restrict__ W2,
    const float* __restrict__ W3, const float* __restrict__ W4,
    uint16_t* __restrict__ W2bf, uint16_t* __restrict__ W3Tbf,
    uint16_t* __restrict__ W1Tbf, uint16_t* __restrict__ W4bf,
    float* __restrict__ W2Tf, float* __restrict__ W3Tf,
    float* __restrict__ W1Tf, float* __restrict__ W4Tf) {
  int i = blockIdx.x * 256 + threadIdx.x;
  if (i < 262144) {
    W2bf[i] = f2bf(W2[i]);
  } else if (i < 524288) {
    int j = i - 262144;
    int r = j >> 9, c = j & 511;
    float v = W3[c * 512 + r];
    W3Tbf[j] = f2bf(v);
    W3Tf[j] = v;
  } else if (i < 786432) {
    int j = i - 524288;
    int r = j >> 9, c = j & 511;
    W2Tf[j] = W2[c * 512 + r];
  } else if (i < 819200) {
    int j = i - 786432;
    int d = j >> 9, k = j & 511;
    float v = W1[k * 64 + d];
    W1Tbf[j] = f2bf(v);
    W1Tf[j] = v;
  } else if (i < 851968) {
    int j = i - 819200;
    W4bf[j] = f2bf(W4[j]);
  } else if (i < 884736) {
    int j = i - 851968;
    int k = j >> 6, d = j & 63;
    W4Tf[j] = W4[d * 512 + k];
  }
}

// ---------------- forward (fp32): masks + 0.5*||s||^2 ----------------
// 512 threads = 8 waves, 4 samples per block, 512 blocks.
// Thread j computes hidden unit j for all 4 samples; weight reads coalesced
// via transposed layout; activations packed [k][s] so one ds_read_b128
// broadcast feeds 4 samples.
__global__ __launch_bounds__(512) void forward_kernel(
    const float* __restrict__ x,
    const float* __restrict__ W1Tf, const float* __restrict__ b1,
    const float* __restrict__ W2Tf, const float* __restrict__ b2,
    const float* __restrict__ W3Tf, const float* __restrict__ b3,
    const float* __restrict__ W4Tf, const float* __restrict__ b4,
    uint16_t* __restrict__ m1u, uint16_t* __restrict__ m2u,
    uint16_t* __restrict__ m3u, float* __restrict__ out) {
  __shared__ float xp[64][4];
  __shared__ float hp[2][512][4];
  const int t = threadIdx.x;
  const int b0 = blockIdx.x * 4;

  if (t < 256) {
    const int k = t >> 2, s = t & 3;
    xp[k][s] = x[(size_t)(b0 + s) * 64 + k];
  }
  __syncthreads();

  const int j = t;
  // ---- layer 1 (K=64) ----
  {
    const float bj = b1[j];
    float a0 = bj, a1 = bj, a2 = bj, a3 = bj;
#pragma unroll 8
    for (int k = 0; k < 64; ++k) {
      const float w = W1Tf[k * 512 + j];
      const float4 h = *(const float4*)(&xp[k][0]);
      a0 = fmaf(w, h.x, a0); a1 = fmaf(w, h.y, a1);
      a2 = fmaf(w, h.z, a2); a3 = fmaf(w, h.w, a3);
    }
    const float av[4] = {a0, a1, a2, a3};
    float4 r;
    float* rp = (float*)&r;
#pragma unroll
    for (int s = 0; s < 4; ++s) {
      const bool p = av[s] > 0.f;
      m1u[(size_t)(b0 + s) * 512 + j] = p ? (uint16_t)0xFFFFu : (uint16_t)0u;
      rp[s] = p ? av[s] : 0.f;
    }
    *(float4*)(&hp[0][j][0]) = r;
  }
  __syncthreads();

  // ---- layer 2 (K=512) ----
  {
    const float bj = b2[j];
    float a0 = bj, a1 = bj, a2 = bj, a3 = bj;
#pragma unroll 8
    for (int k = 0; k < 512; ++k) {
      const float w = W2Tf[k * 512 + j];
      const float4 h = *(const float4*)(&hp[0][k][0]);
      a0 = fmaf(w, h.x, a0); a1 = fmaf(w, h.y, a1);
      a2 = fmaf(w, h.z, a2); a3 = fmaf(w, h.w, a3);
    }
    const float av[4] = {a0, a1, a2, a3};
    float4 r;
    float* rp = (float*)&r;
#pragma unroll
    for (int s = 0; s < 4; ++s) {
      const bool p = av[s] > 0.f;
      m2u[(size_t)(b0 + s) * 512 + j] = p ? (uint16_t)0xFFFFu : (uint16_t)0u;
      rp[s] = p ? av[s] : 0.f;
    }
    *(float4*)(&hp[1][j][0]) = r;
  }
  __syncthreads();

  // ---- layer 3 (K=512) ----
  {
    const float bj = b3[j];
    float a0 = bj, a1 = bj, a2 = bj, a3 = bj;
#pragma unroll 8
    for (int k = 0; k < 512; ++k) {
      const float w = W3Tf[k * 512 + j];
      const float4 h = *(const float4*)(&hp[1][k][0]);
      a0 = fmaf(w, h.x, a0); a1 = fmaf(w, h.y, a1);
      a2 = fmaf(w, h.z, a2); a3 = fmaf(w, h.w, a3);
    }
    const float av[4] = {a0, a1, a2, a3};
    float4 r;
    float* rp = (float*)&r;
#pragma unroll
    for (int s = 0; s < 4; ++s) {
      const bool p = av[s] > 0.f;
      m3u[(size_t)(b0 + s) * 512 + j] = p ? (uint16_t)0xFFFFu : (uint16_t)0u;
      rp[s] = p ? av[s] : 0.f;
    }
    *(float4*)(&hp[0][j][0]) = r;
  }
  __syncthreads();

  // ---- layer 4 (K=512) + 0.5*||s||^2 ----
  if (t < 256) {
    const int s = t >> 6;  // wave == sample
    const int d = t & 63;
    float acc = b4[d];
#pragma unroll 8
    for (int k = 0; k < 512; ++k) {
      acc = fmaf(W4Tf[k * 64 + d], hp[0][k][s], acc);
    }
    float sq = acc * acc;
#pragma unroll
    for (int off = 32; off; off >>= 1) sq += __shfl_down(sq, off, 64);
    if (d == 0) out[b0 + s] = 0.5f * sq;
  }
}

// ---------------- divergence: dual bf16 MFMA GEMM + elementwise contraction ----------------
// grid (1024 sample-groups of 2, 4 row-tiles of 128); block 256 = 4 waves.
// wave (sLoc = wv&1, rh = wv>>1): sample g*2+sLoc, rows rowB0 + rh*64 .. +64, cols 0..64.
// LPAD 40: row stride 80 B = 20 dwords -> lane*20 mod 32 spreads 8 bank groups,
// 2-way aliasing only (free). LDS total 40 KB -> 4 blocks/CU.
#define LPAD 40

__global__ __launch_bounds__(256, 4) void div_kernel(
    const uint16_t* __restrict__ W2bf, const uint16_t* __restrict__ W3Tbf,
    const uint16_t* __restrict__ W1Tbf, const uint16_t* __restrict__ W4bf,
    const uint16_t* __restrict__ m1u, const uint16_t* __restrict__ m2u,
    const uint16_t* __restrict__ m3u, float* __restrict__ out) {
  __shared__ uint16_t A2s[128][LPAD];      // W2 tile   [row][k]
  __shared__ uint16_t A3s[128][LPAD];      // W3T tile  [row][k]
  __shared__ uint16_t B1s[2][64][LPAD];    // (m1.*W1T) [sample][d][k]
  __shared__ uint16_t B4s[2][64][LPAD];    // (m3.*W4)  [sample][d][k]

  const int t = threadIdx.x;
  const int lane = t & 63;
  const int wv = t >> 6;
  const int sLoc = wv & 1;
  const int rh = wv >> 1;
  const int l15 = lane & 15;
  const int quad = lane >> 4;
  const int g = blockIdx.x;
  const int rowB0 = blockIdx.y * 128;
  const int b = g * 2 + sLoc;

  f32x4 accC[4][4], accG[4][4];
#pragma unroll
  for (int it = 0; it < 4; ++it)
#pragma unroll
    for (int jt = 0; jt < 4; ++jt) {
      accC[it][jt] = (f32x4){0.f, 0.f, 0.f, 0.f};
      accG[it][jt] = (f32x4){0.f, 0.f, 0.f, 0.f};
    }

  // staging maps: A: 128 rows x 32 k -> thread (row = t>>1, 16 k each)
  const int arow = t >> 1, aseg = t & 1;
  // B: 2 samples x 64 d x 32 k -> thread
  const int sB = t >> 7;
  const int dB = (t & 127) >> 1;
  const int bseg = t & 1;
  const int bS = g * 2 + sB;

  for (int kc = 0; kc < 16; ++kc) {
    const int k0 = kc * 32;
    __syncthreads();
    {
      const uint4* s2 = (const uint4*)(W2bf + (size_t)(rowB0 + arow) * 512 + k0 + aseg * 16);
      const uint4* s3 = (const uint4*)(W3Tbf + (size_t)(rowB0 + arow) * 512 + k0 + aseg * 16);
      uint4* d2 = (uint4*)(&A2s[arow][aseg * 16]);
      uint4* d3 = (uint4*)(&A3s[arow][aseg * 16]);
      d2[0] = s2[0]; d2[1] = s2[1];
      d3[0] = s3[0]; d3[1] = s3[1];
    }
    {
      const uint4* w1p = (const uint4*)(W1Tbf + (size_t)dB * 512 + k0 + bseg * 16);
      const uint4* w4p = (const uint4*)(W4bf + (size_t)dB * 512 + k0 + bseg * 16);
      const uint4* m1p = (const uint4*)(m1u + (size_t)bS * 512 + k0 + bseg * 16);
      const uint4* m3p = (const uint4*)(m3u + (size_t)bS * 512 + k0 + bseg * 16);
      uint4* d1 = (uint4*)(&B1s[sB][dB][bseg * 16]);
      uint4* d4 = (uint4*)(&B4s[sB][dB][bseg * 16]);
#pragma unroll
      for (int i = 0; i < 2; ++i) {
        uint4 w = w1p[i]; uint4 m = m1p[i];
        d1[i] = make_uint4(w.x & m.x, w.y & m.y, w.z & m.z, w.w & m.w);
        w = w4p[i]; m = m3p[i];
        d4[i] = make_uint4(w.x & m.x, w.y & m.y, w.z & m.z, w.w & m.w);
      }
    }
    __syncthreads();

    short8 b1f[4], b4f[4];
#pragma unroll
    for (int jt = 0; jt < 4; ++jt) {
      b1f[jt] = *(const short8*)(&B1s[sLoc][jt * 16 + l15][quad * 8]);
      b4f[jt] = *(const short8*)(&B4s[sLoc][jt * 16 + l15][quad * 8]);
    }
#pragma unroll
    for (int it = 0; it < 4; ++it) {
      const short8 a2 = *(const short8*)(&A2s[rh * 64 + it * 16 + l15][quad * 8]);
      const short8 a3 = *(const short8*)(&A3s[rh * 64 + it * 16 + l15][quad * 8]);
#pragma unroll
      for (int jt = 0; jt < 4; ++jt) {
        accC[it][jt] = __builtin_amdgcn_mfma_f32_16x16x32_bf16(a2, b1f[jt], accC[it][jt], 0, 0, 0);
        accG[it][jt] = __builtin_amdgcn_mfma_f32_16x16x32_bf16(a3, b4f[jt], accG[it][jt], 0, 0, 0);
      }
    }
  }

  // epilogue: dsum = sum m2[row] * C .* G ; C/D layout: row = quad*4+reg, col = l15
  float dsum = 0.f;
#pragma unroll
  for (int it = 0; it < 4; ++it) {
    const int row = rowB0 + rh * 64 + it * 16 + quad * 4;
    const uint2 mm = *(const uint2*)(m2u + (size_t)b * 512 + row);
    const float w0 = (mm.x & 0xFFFFu) ? 1.f : 0.f;
    const float w1 = (mm.x >> 16) ? 1.f : 0.f;
    const float w2 = (mm.y & 0xFFFFu) ? 1.f : 0.f;
    const float w3 = (mm.y >> 16) ? 1.f : 0.f;
#pragma unroll
    for (int jt = 0; jt < 4; ++jt) {
      dsum = fmaf(w0, accC[it][jt][0] * accG[it][jt][0], dsum);
      dsum = fmaf(w1, accC[it][jt][1] * accG[it][jt][1], dsum);
      dsum = fmaf(w2, accC[it][jt][2] * accG[it][jt][2], dsum);
      dsum = fmaf(w3, accC[it][jt][3] * accG[it][jt][3], dsum);
    }
  }
#pragma unroll
  for (int off = 32; off; off >>= 1) dsum += __shfl_down(dsum, off, 64);
  if (lane == 0) atomicAdd(out + b, dsum);
}

extern "C" void kernel_launch(void* const* d_in, const int* in_sizes, int n_in,
                              void* d_out, int out_size, void* d_ws, size_t ws_size,
                              hipStream_t stream) {
  const float* x  = (const float*)d_in[0];
  const float* W1 = (const float*)d_in[1];
  const float* b1 = (const float*)d_in[2];
  const float* W2 = (const float*)d_in[3];
  const float* b2 = (const float*)d_in[4];
  const float* W3 = (const float*)d_in[5];
  const float* b3 = (const float*)d_in[6];
  const float* W4 = (const float*)d_in[7];
  const float* b4 = (const float*)d_in[8];
  float* out = (float*)d_out;

  // workspace layout (bytes):
  //   W2bf 524288 | W3Tbf 524288 | W1Tbf 65536 | W4bf 65536
  //   W2Tf 1048576 | W3Tf 1048576 | W1Tf 131072 | W4Tf 131072
  //   m1u/m2u/m3u 3x2097152  => total 9,830,400 B
  char* ws = (char*)d_ws;
  uint16_t* W2bf  = (uint16_t*)(ws + 0);
  uint16_t* W3Tbf = (uint16_t*)(ws + 524288);
  uint16_t* W1Tbf = (uint16_t*)(ws + 1048576);
  uint16_t* W4bf  = (uint16_t*)(ws + 1114112);
  float*    W2Tf  = (float*)(ws + 1179648);
  float*    W3Tf  = (float*)(ws + 2228224);
  float*    W1Tf  = (float*)(ws + 3276800);
  float*    W4Tf  = (float*)(ws + 3407872);
  uint16_t* m1u   = (uint16_t*)(ws + 3538944);
  uint16_t* m2u   = (uint16_t*)(ws + 5636096);
  uint16_t* m3u   = (uint16_t*)(ws + 7733248);
  if (ws_size < 9830400) return;  // need ~9.4 MB

  convert_kernel<<<3456, 256, 0, stream>>>(W1, W2, W3, W4,
                                           W2bf, W3Tbf, W1Tbf, W4bf,
                                           W2Tf, W3Tf, W1Tf, W4Tf);
  forward_kernel<<<512, 512, 0, stream>>>(x, W1Tf, b1, W2Tf, b2, W3Tf, b3,
                                          W4Tf, b4, m1u, m2u, m3u, out);
  div_kernel<<<dim3(1024, 4), 256, 0, stream>>>(W2bf, W3Tbf, W1Tbf, W4bf,
                                                m1u, m2u, m3u, out);
}

// Round 3
// 471.950 us; speedup vs baseline: 1.9459x; 1.9459x over previous
//
#include <hip/hip_runtime.h>
#include <stdint.h>

// ScoreMatching: B=2048, D=64, H=512.
// out[b] = 0.5*||s_b||^2 + tr(W4 M3 W3 M2 W2 M1 W1)_b
// div_b = sum_{i,d} m2[i] * C[i,d] * G[i,d]
//   C = W2 @ (M1 .* W1)      [512 x 64]
//   G = W3^T @ (M3 .* W4^T)  [512 x 64]
// Forward in fp32 (precision for ||s||^2). Divergence in bf16 MFMA with
// bit-packed ReLU masks (ballot-packed in forward, expanded to AND-masks in
// the div kernel). B-operands stream straight from global (L1/L2-resident
// weights); only the A-tiles go through LDS.
// NOTE: accC+accG = 128 AGPRs/wave; with ~100 VGPRs that is ~230 of the 512
// unified regs -> 2 waves/EU max. __launch_bounds__(256,2). Never ask for 4:
// R2 showed the compiler spills accumulators to scratch (1.4 GB HBM fetch).

typedef __attribute__((ext_vector_type(8))) short short8;
typedef __attribute__((ext_vector_type(4))) float f32x4;

union U16x8 {
  uint4 u;
  short8 s;
};

__device__ __forceinline__ uint16_t f2bf(float f) {
  uint32_t u = __float_as_uint(f);
  uint32_t lsb = (u >> 16) & 1u;
  u += 0x7FFFu + lsb;  // round-to-nearest-even
  return (uint16_t)(u >> 16);
}

// ---------------- convert: bf16 copies/transposes + fp32 transposes ----------------
__global__ __launch_bounds__(256) void convert_kernel(
    const float* __restrict__ W1, const float* __restrict__ W2,
    const float* __restrict__ W3, const float* __restrict__ W4,
    uint16_t* __restrict__ W2bf, uint16_t* __restrict__ W3Tbf,
    uint16_t* __restrict__ W1Tbf, uint16_t* __restrict__ W4bf,
    float* __restrict__ W2Tf, float* __restrict__ W3Tf,
    float* __restrict__ W1Tf, float* __restrict__ W4Tf) {
  int i = blockIdx.x * 256 + threadIdx.x;
  if (i < 262144) {
    W2bf[i] = f2bf(W2[i]);
  } else if (i < 524288) {
    int j = i - 262144;
    int r = j >> 9, c = j & 511;
    float v = W3[c * 512 + r];
    W3Tbf[j] = f2bf(v);
    W3Tf[j] = v;
  } else if (i < 786432) {
    int j = i - 524288;
    int r = j >> 9, c = j & 511;
    W2Tf[j] = W2[c * 512 + r];
  } else if (i < 819200) {
    int j = i - 786432;
    int d = j >> 9, k = j & 511;
    float v = W1[k * 64 + d];
    W1Tbf[j] = f2bf(v);
    W1Tf[j] = v;
  } else if (i < 851968) {
    int j = i - 819200;
    W4bf[j] = f2bf(W4[j]);
  } else if (i < 884736) {
    int j = i - 851968;
    int k = j >> 6, d = j & 63;
    W4Tf[j] = W4[d * 512 + k];
  }
}

// ---------------- forward (fp32): packed masks + 0.5*||s||^2 ----------------
// 512 threads = 8 waves, 8 samples per block, 256 blocks.
// hp stride 12 floats (48 B): 16B-aligned float4s, 2-way LDS write aliasing (free).
__device__ __forceinline__ void layer512(
    const float* __restrict__ Win, const float* __restrict__ bias,
    const float (*__restrict__ src)[12], float (*__restrict__ dst)[12],
    uint64_t* __restrict__ mp, int b0, int t) {
  const int j = t, wv = t >> 6, lane = t & 63;
  const float bj = bias[j];
  float a[8];
#pragma unroll
  for (int s = 0; s < 8; ++s) a[s] = bj;
#pragma unroll 4
  for (int k = 0; k < 512; ++k) {
    const float w = Win[k * 512 + j];
    const float4 h0 = *(const float4*)(&src[k][0]);
    const float4 h1 = *(const float4*)(&src[k][4]);
    a[0] = fmaf(w, h0.x, a[0]); a[1] = fmaf(w, h0.y, a[1]);
    a[2] = fmaf(w, h0.z, a[2]); a[3] = fmaf(w, h0.w, a[3]);
    a[4] = fmaf(w, h1.x, a[4]); a[5] = fmaf(w, h1.y, a[5]);
    a[6] = fmaf(w, h1.z, a[6]); a[7] = fmaf(w, h1.w, a[7]);
  }
  float r[8];
#pragma unroll
  for (int s = 0; s < 8; ++s) {
    const bool p = a[s] > 0.f;
    unsigned long long bb = __ballot(p);  // bit L = unit 64*wv+L of sample b0+s
    if (lane == 0) mp[(size_t)(b0 + s) * 8 + wv] = bb;
    r[s] = p ? a[s] : 0.f;
  }
  *(float4*)(&dst[j][0]) = make_float4(r[0], r[1], r[2], r[3]);
  *(float4*)(&dst[j][4]) = make_float4(r[4], r[5], r[6], r[7]);
}

__global__ __launch_bounds__(512) void forward_kernel(
    const float* __restrict__ x,
    const float* __restrict__ W1Tf, const float* __restrict__ b1,
    const float* __restrict__ W2Tf, const float* __restrict__ b2,
    const float* __restrict__ W3Tf, const float* __restrict__ b3,
    const float* __restrict__ W4Tf, const float* __restrict__ b4,
    uint64_t* __restrict__ m1p, uint64_t* __restrict__ m2p,
    uint64_t* __restrict__ m3p, float* __restrict__ out) {
  __shared__ float xp[64][8];
  __shared__ float hp[2][512][12];
  const int t = threadIdx.x;
  const int b0 = blockIdx.x * 8;
  const int wv = t >> 6, lane = t & 63;

  {
    const int k = t >> 3, s = t & 7;
    xp[k][s] = x[(size_t)(b0 + s) * 64 + k];
  }
  __syncthreads();

  // ---- layer 1 (K=64) ----
  {
    const int j = t;
    const float bj = b1[j];
    float a[8];
#pragma unroll
    for (int s = 0; s < 8; ++s) a[s] = bj;
#pragma unroll 8
    for (int k = 0; k < 64; ++k) {
      const float w = W1Tf[k * 512 + j];
      const float4 h0 = *(const float4*)(&xp[k][0]);
      const float4 h1 = *(const float4*)(&xp[k][4]);
      a[0] = fmaf(w, h0.x, a[0]); a[1] = fmaf(w, h0.y, a[1]);
      a[2] = fmaf(w, h0.z, a[2]); a[3] = fmaf(w, h0.w, a[3]);
      a[4] = fmaf(w, h1.x, a[4]); a[5] = fmaf(w, h1.y, a[5]);
      a[6] = fmaf(w, h1.z, a[6]); a[7] = fmaf(w, h1.w, a[7]);
    }
    float r[8];
#pragma unroll
    for (int s = 0; s < 8; ++s) {
      const bool p = a[s] > 0.f;
      unsigned long long bb = __ballot(p);
      if (lane == 0) m1p[(size_t)(b0 + s) * 8 + wv] = bb;
      r[s] = p ? a[s] : 0.f;
    }
    *(float4*)(&hp[0][j][0]) = make_float4(r[0], r[1], r[2], r[3]);
    *(float4*)(&hp[0][j][4]) = make_float4(r[4], r[5], r[6], r[7]);
  }
  __syncthreads();
  layer512(W2Tf, b2, hp[0], hp[1], m2p, b0, t);
  __syncthreads();
  layer512(W3Tf, b3, hp[1], hp[0], m3p, b0, t);
  __syncthreads();

  // ---- layer 4 (K=512) + 0.5*||s||^2 : wave wv handles sample b0+wv ----
  {
    const int s = wv;
    const int d = lane;
    float acc = b4[d];
#pragma unroll 8
    for (int k = 0; k < 512; ++k) {
      acc = fmaf(W4Tf[k * 64 + d], hp[0][k][s], acc);
    }
    float sq = acc * acc;
#pragma unroll
    for (int off = 32; off; off >>= 1) sq += __shfl_down(sq, off, 64);
    if (d == 0) out[b0 + s] = 0.5f * sq;
  }
}

// ---------------- divergence: dual bf16 MFMA GEMM, B from global + bitmasks ----------------
// grid (1024 sample-groups of 2, 4 row-tiles of 128); block 256 = 4 waves.
// wave (sLoc=wv&1, rh=wv>>1): sample g*2+sLoc, rows rowB0+rh*64..+64, cols 0..64.
// LPAD 40: row stride 80 B -> 2-way bank aliasing only (free, m136).
#define LPAD 40

__device__ __forceinline__ void expand_mask(uint32_t byte8, uint32_t mk[4]) {
  // 8 mask bits (k ascending) -> 4 dwords of bf16 lane-AND-masks
#pragma unroll
  for (int i = 0; i < 4; ++i) {
    mk[i] = (((byte8 >> (2 * i)) & 1u) ? 0x0000FFFFu : 0u) |
            (((byte8 >> (2 * i + 1)) & 1u) ? 0xFFFF0000u : 0u);
  }
}

__global__ __launch_bounds__(256, 2) void div_kernel(
    const uint16_t* __restrict__ W2bf, const uint16_t* __restrict__ W3Tbf,
    const uint16_t* __restrict__ W1Tbf, const uint16_t* __restrict__ W4bf,
    const uint32_t* __restrict__ m1p, const uint32_t* __restrict__ m2p,
    const uint32_t* __restrict__ m3p, float* __restrict__ out) {
  __shared__ uint16_t A2s[128][LPAD];  // W2 tile   [row][k]
  __shared__ uint16_t A3s[128][LPAD];  // W3T tile  [row][k]

  const int t = threadIdx.x;
  const int lane = t & 63;
  const int wv = t >> 6;
  const int sLoc = wv & 1;
  const int rh = wv >> 1;
  const int l15 = lane & 15;
  const int quad = lane >> 4;
  const int g = blockIdx.x;
  const int rowB0 = blockIdx.y * 128;
  const int b = g * 2 + sLoc;

  f32x4 accC[4][4], accG[4][4];
#pragma unroll
  for (int it = 0; it < 4; ++it)
#pragma unroll
    for (int jt = 0; jt < 4; ++jt) {
      accC[it][jt] = (f32x4){0.f, 0.f, 0.f, 0.f};
      accG[it][jt] = (f32x4){0.f, 0.f, 0.f, 0.f};
    }

  const int arow = t >> 1, aseg = t & 1;
  const uint32_t* m1w = m1p + (size_t)b * 16;
  const uint32_t* m3w = m3p + (size_t)b * 16;

  for (int kc = 0; kc < 16; ++kc) {
    const int k0 = kc * 32;
    __syncthreads();
    {
      const uint4* s2 = (const uint4*)(W2bf + (size_t)(rowB0 + arow) * 512 + k0 + aseg * 16);
      const uint4* s3 = (const uint4*)(W3Tbf + (size_t)(rowB0 + arow) * 512 + k0 + aseg * 16);
      uint4* d2 = (uint4*)(&A2s[arow][aseg * 16]);
      uint4* d3 = (uint4*)(&A3s[arow][aseg * 16]);
      d2[0] = s2[0]; d2[1] = s2[1];
      d3[0] = s3[0]; d3[1] = s3[1];
    }
    __syncthreads();

    // ---- C pass: accC += A2 * (m1 .* W1T)^T ----
    {
      const uint32_t m1d = __builtin_amdgcn_readfirstlane(m1w[kc]);
      uint32_t mk[4];
      expand_mask((m1d >> (quad * 8)) & 0xFFu, mk);
      short8 bf[4];
#pragma unroll
      for (int jt = 0; jt < 4; ++jt) {
        const int d = jt * 16 + l15;
        U16x8 u;
        u.u = *(const uint4*)(W1Tbf + (size_t)d * 512 + k0 + quad * 8);
        u.u.x &= mk[0]; u.u.y &= mk[1]; u.u.z &= mk[2]; u.u.w &= mk[3];
        bf[jt] = u.s;
      }
#pragma unroll
      for (int it = 0; it < 4; ++it) {
        const short8 a2 = *(const short8*)(&A2s[rh * 64 + it * 16 + l15][quad * 8]);
#pragma unroll
        for (int jt = 0; jt < 4; ++jt)
          accC[it][jt] = __builtin_amdgcn_mfma_f32_16x16x32_bf16(a2, bf[jt], accC[it][jt], 0, 0, 0);
      }
    }
    // ---- G pass: accG += A3 * (m3 .* W4)^T ----
    {
      const uint32_t m3d = __builtin_amdgcn_readfirstlane(m3w[kc]);
      uint32_t mk[4];
      expand_mask((m3d >> (quad * 8)) & 0xFFu, mk);
      short8 bf[4];
#pragma unroll
      for (int jt = 0; jt < 4; ++jt) {
        const int d = jt * 16 + l15;
        U16x8 u;
        u.u = *(const uint4*)(W4bf + (size_t)d * 512 + k0 + quad * 8);
        u.u.x &= mk[0]; u.u.y &= mk[1]; u.u.z &= mk[2]; u.u.w &= mk[3];
        bf[jt] = u.s;
      }
#pragma unroll
      for (int it = 0; it < 4; ++it) {
        const short8 a3 = *(const short8*)(&A3s[rh * 64 + it * 16 + l15][quad * 8]);
#pragma unroll
        for (int jt = 0; jt < 4; ++jt)
          accG[it][jt] = __builtin_amdgcn_mfma_f32_16x16x32_bf16(a3, bf[jt], accG[it][jt], 0, 0, 0);
      }
    }
  }

  // epilogue: dsum = sum m2[row] * C .* G ; C/D layout: row = quad*4+reg, col = l15
  const uint32_t* m2w = m2p + (size_t)b * 16;
  float dsum = 0.f;
#pragma unroll
  for (int it = 0; it < 4; ++it) {
    const int rloc = rh * 64 + it * 16 + quad * 4;
    const uint32_t md = m2w[(rowB0 + rloc) >> 5];
    const uint32_t bits = (md >> (rloc & 31)) & 0xFu;
    const float w0 = (bits & 1u) ? 1.f : 0.f;
    const float w1 = (bits & 2u) ? 1.f : 0.f;
    const float w2 = (bits & 4u) ? 1.f : 0.f;
    const float w3 = (bits & 8u) ? 1.f : 0.f;
#pragma unroll
    for (int jt = 0; jt < 4; ++jt) {
      dsum = fmaf(w0, accC[it][jt][0] * accG[it][jt][0], dsum);
      dsum = fmaf(w1, accC[it][jt][1] * accG[it][jt][1], dsum);
      dsum = fmaf(w2, accC[it][jt][2] * accG[it][jt][2], dsum);
      dsum = fmaf(w3, accC[it][jt][3] * accG[it][jt][3], dsum);
    }
  }
#pragma unroll
  for (int off = 32; off; off >>= 1) dsum += __shfl_down(dsum, off, 64);
  if (lane == 0) atomicAdd(out + b, dsum);
}

extern "C" void kernel_launch(void* const* d_in, const int* in_sizes, int n_in,
                              void* d_out, int out_size, void* d_ws, size_t ws_size,
                              hipStream_t stream) {
  const float* x  = (const float*)d_in[0];
  const float* W1 = (const float*)d_in[1];
  const float* b1 = (const float*)d_in[2];
  const float* W2 = (const float*)d_in[3];
  const float* b2 = (const float*)d_in[4];
  const float* W3 = (const float*)d_in[5];
  const float* b3 = (const float*)d_in[6];
  const float* W4 = (const float*)d_in[7];
  const float* b4 = (const float*)d_in[8];
  float* out = (float*)d_out;

  // workspace layout (bytes), total 3,932,160:
  char* ws = (char*)d_ws;
  uint16_t* W2bf  = (uint16_t*)(ws + 0);        // 524288
  uint16_t* W3Tbf = (uint16_t*)(ws + 524288);   // 524288
  uint16_t* W1Tbf = (uint16_t*)(ws + 1048576);  // 65536
  uint16_t* W4bf  = (uint16_t*)(ws + 1114112);  // 65536
  float*    W2Tf  = (float*)(ws + 1179648);     // 1048576
  float*    W3Tf  = (float*)(ws + 2228224);     // 1048576
  float*    W1Tf  = (float*)(ws + 3276800);     // 131072
  float*    W4Tf  = (float*)(ws + 3407872);     // 131072
  uint64_t* m1p   = (uint64_t*)(ws + 3538944);  // 131072 (2048 x 512 bits)
  uint64_t* m2p   = (uint64_t*)(ws + 3670016);  // 131072
  uint64_t* m3p   = (uint64_t*)(ws + 3801088);  // 131072
  if (ws_size < 3932160) return;

  convert_kernel<<<3456, 256, 0, stream>>>(W1, W2, W3, W4,
                                           W2bf, W3Tbf, W1Tbf, W4bf,
                                           W2Tf, W3Tf, W1Tf, W4Tf);
  forward_kernel<<<256, 512, 0, stream>>>(x, W1Tf, b1, W2Tf, b2, W3Tf, b3,
                                          W4Tf, b4, m1p, m2p, m3p, out);
  div_kernel<<<dim3(1024, 4), 256, 0, stream>>>(W2bf, W3Tbf, W1Tbf, W4bf,
                                                (const uint32_t*)m1p,
                                                (const uint32_t*)m2p,
                                                (const uint32_t*)m3p, out);
}

// Round 4
// 326.107 us; speedup vs baseline: 2.8162x; 1.4472x over previous
//
#include <hip/hip_runtime.h>
#include <stdint.h>

// ScoreMatching: B=2048, D=64, H=512.
// out[b] = 0.5*||s_b||^2 + tr(W4 M3 W3 M2 W2 M1 W1)_b
// div_b = sum_{i,d} m2[i] * C[i,d] * G[i,d]
//   C = W2 @ (M1 .* W1)      [512 x 64]   A-frag = W2 rows,  B-frag = masked W1T rows
//   G = W3^T @ (M3 .* W4^T)  [512 x 64]   A-frag = W3T rows, B-frag = masked W4 rows
// R4 design:
//  - div kernel: NO LDS, NO barriers. A and B pre-swizzled in global into exact
//    16x16x32 MFMA fragment order -> every frag load is one coalesced 1KB
//    global_load_dwordx4 per wave. B (128 KB) is L1-hot; A (1 MB) streams from L2.
//    Masks are bit-packed (u32 word per 32 units), expanded to bf16 AND-masks in regs.
//    R3 failure mode (per-lane row gather, 64 lines/instr) is gone.
//  - acc = 128 AGPRs/wave + ~100 VGPR: keep __launch_bounds__(256,2).
//    R2 lesson: never ask for >2 waves/EU with this accumulator tile (spills).
//  - forward: 4 units x 4 samples per thread -> 16 FMA per 16B LDS read (was 8
//    FMA per 32B): VALU-bound instead of LDS-bound.

typedef __attribute__((ext_vector_type(8))) short short8;
typedef __attribute__((ext_vector_type(4))) float f32x4;

union U16x8 {
  uint4 u;
  short8 s;
};

__device__ __forceinline__ uint16_t f2bf(float f) {
  uint32_t u = __float_as_uint(f);
  uint32_t lsb = (u >> 16) & 1u;
  u += 0x7FFFu + lsb;  // round-to-nearest-even
  return (uint16_t)(u >> 16);
}

// ---------------- convert: build swizzled bf16 fragments + fp32 transposes ----------------
// Fragment order (16x16x32 bf16 MFMA): lane = quad*16 + l15 holds 8 contiguous
// bf16 = 16 B; A-frag element (m=l15, k=quad*8+j); B-frag (n=l15, k=quad*8+j).
// A2swz[((r16*16 + kc)*64 + lane)*8 + j] = W2 [r16*16+l15][kc*32+quad*8+j]
// A3swz[  same index                   ] = W3T[r16*16+l15][kc*32+quad*8+j]
// B1swz[((kc*4 + jt)*64 + lane)*8 + j]  = W1T[jt*16+l15 ][kc*32+quad*8+j]
// B4swz[  same index                 ]  = W4 [jt*16+l15 ][kc*32+quad*8+j]
__global__ __launch_bounds__(256) void convert_kernel(
    const float* __restrict__ W1, const float* __restrict__ W2,
    const float* __restrict__ W3, const float* __restrict__ W4,
    uint16_t* __restrict__ A2swz, uint16_t* __restrict__ A3swz,
    uint16_t* __restrict__ B1swz, uint16_t* __restrict__ B4swz,
    float* __restrict__ W2Tf, float* __restrict__ W3Tf,
    float* __restrict__ W1Tf, float* __restrict__ W4Tf) {
  const int i = blockIdx.x * 256 + threadIdx.x;
  if (i < 262144) {  // A2swz
    const int e = i;
    const int f = e >> 3, j = e & 7;
    const int lane = f & 63, fk = f >> 6;
    const int kc = fk & 15, r16 = fk >> 4;
    const int l15 = lane & 15, quad = lane >> 4;
    const int row = r16 * 16 + l15, col = kc * 32 + quad * 8 + j;
    A2swz[e] = f2bf(W2[row * 512 + col]);
  } else if (i < 524288) {  // A3swz (= W3 transposed)
    const int e = i - 262144;
    const int f = e >> 3, j = e & 7;
    const int lane = f & 63, fk = f >> 6;
    const int kc = fk & 15, r16 = fk >> 4;
    const int l15 = lane & 15, quad = lane >> 4;
    const int row = r16 * 16 + l15, col = kc * 32 + quad * 8 + j;
    A3swz[e] = f2bf(W3[col * 512 + row]);
  } else if (i < 557056) {  // B1swz (= W1 transposed)
    const int e = i - 524288;
    const int f = e >> 3, j = e & 7;
    const int lane = f & 63, fk = f >> 6;
    const int kc = fk >> 2, jt = fk & 3;
    const int l15 = lane & 15, quad = lane >> 4;
    const int d = jt * 16 + l15, col = kc * 32 + quad * 8 + j;
    B1swz[e] = f2bf(W1[col * 64 + d]);
  } else if (i < 589824) {  // B4swz (= W4 row-major)
    const int e = i - 557056;
    const int f = e >> 3, j = e & 7;
    const int lane = f & 63, fk = f >> 6;
    const int kc = fk >> 2, jt = fk & 3;
    const int l15 = lane & 15, quad = lane >> 4;
    const int d = jt * 16 + l15, col = kc * 32 + quad * 8 + j;
    B4swz[e] = f2bf(W4[d * 512 + col]);
  } else if (i < 851968) {  // W2Tf [k][j]
    const int e = i - 589824;
    const int k = e >> 9, jj = e & 511;
    W2Tf[e] = W2[jj * 512 + k];
  } else if (i < 1114112) {  // W3Tf [k][j]
    const int e = i - 851968;
    const int k = e >> 9, jj = e & 511;
    W3Tf[e] = W3[jj * 512 + k];
  } else if (i < 1146880) {  // W1Tf [k][j], k<64
    const int e = i - 1114112;
    const int k = e >> 9, jj = e & 511;
    W1Tf[e] = W1[jj * 64 + k];
  } else if (i < 1179648) {  // W4Tf [k][d]
    const int e = i - 1146880;
    const int k = e >> 6, d = e & 63;
    W4Tf[e] = W4[d * 512 + k];
  }
}

// ---------------- forward (fp32): packed masks + 0.5*||s||^2 ----------------
// 256 threads = 4 waves, 8 samples/block, 256 blocks.
// Thread: sh = t>>7 (sample half: 4 samples), jq = t&127 -> units j4..j4+3.
// Per k: one LDS float4 (4 samples) + one global float4 (4 units) -> 16 FMA.
// Masks: nibble per (thread, sample) -> LDS atomicOr into u32 words; bit u of
// word w = unit w*32+u  (matches div kernel's m?p layout).
__device__ __forceinline__ void fwd_hidden(
    const float* __restrict__ WT, const float* __restrict__ bias,
    const float4* __restrict__ src, float4* __restrict__ dst,
    uint32_t* __restrict__ mw, uint32_t* __restrict__ mglob,
    int sh, int jq, int t, int K) {
  const int j4 = jq * 4;
  float a[4][4];
  {
    const float4 bb = *(const float4*)(bias + j4);
#pragma unroll
    for (int si = 0; si < 4; ++si) {
      a[0][si] = bb.x; a[1][si] = bb.y; a[2][si] = bb.z; a[3][si] = bb.w;
    }
  }
#pragma unroll 4
  for (int k = 0; k < K; ++k) {
    const float4 w = *(const float4*)(WT + (size_t)k * 512 + j4);
    const float4 h = src[k];
    a[0][0] = fmaf(w.x, h.x, a[0][0]); a[0][1] = fmaf(w.x, h.y, a[0][1]);
    a[0][2] = fmaf(w.x, h.z, a[0][2]); a[0][3] = fmaf(w.x, h.w, a[0][3]);
    a[1][0] = fmaf(w.y, h.x, a[1][0]); a[1][1] = fmaf(w.y, h.y, a[1][1]);
    a[1][2] = fmaf(w.y, h.z, a[1][2]); a[1][3] = fmaf(w.y, h.w, a[1][3]);
    a[2][0] = fmaf(w.z, h.x, a[2][0]); a[2][1] = fmaf(w.z, h.y, a[2][1]);
    a[2][2] = fmaf(w.z, h.z, a[2][2]); a[2][3] = fmaf(w.z, h.w, a[2][3]);
    a[3][0] = fmaf(w.w, h.x, a[3][0]); a[3][1] = fmaf(w.w, h.y, a[3][1]);
    a[3][2] = fmaf(w.w, h.z, a[3][2]); a[3][3] = fmaf(w.w, h.w, a[3][3]);
  }
  const int word = jq >> 3, shift = 4 * (jq & 7);
#pragma unroll
  for (int si = 0; si < 4; ++si) {
    uint32_t nib = (a[0][si] > 0.f ? 1u : 0u) | (a[1][si] > 0.f ? 2u : 0u) |
                   (a[2][si] > 0.f ? 4u : 0u) | (a[3][si] > 0.f ? 8u : 0u);
    if (nib) atomicOr(&mw[(sh * 4 + si) * 16 + word], nib << shift);
  }
#pragma unroll
  for (int u = 0; u < 4; ++u) {
    float4 r;
    r.x = a[u][0] > 0.f ? a[u][0] : 0.f;
    r.y = a[u][1] > 0.f ? a[u][1] : 0.f;
    r.z = a[u][2] > 0.f ? a[u][2] : 0.f;
    r.w = a[u][3] > 0.f ? a[u][3] : 0.f;
    dst[j4 + u] = r;
  }
  __syncthreads();
  if (t < 128) {
    mglob[(size_t)(t >> 4) * 16 + (t & 15)] = mw[t];
    mw[t] = 0;
  }
  __syncthreads();
}

__global__ __launch_bounds__(256) void forward_kernel(
    const float* __restrict__ x,
    const float* __restrict__ W1Tf, const float* __restrict__ b1,
    const float* __restrict__ W2Tf, const float* __restrict__ b2,
    const float* __restrict__ W3Tf, const float* __restrict__ b3,
    const float* __restrict__ W4Tf, const float* __restrict__ b4,
    uint32_t* __restrict__ m1p, uint32_t* __restrict__ m2p,
    uint32_t* __restrict__ m3p, float* __restrict__ out) {
  __shared__ float4 xs[2][64];      // [sh][k]
  __shared__ float4 hp[2][2][512];  // [buf][sh][k]
  __shared__ uint32_t mw[128];      // [sample][16 words]
  const int t = threadIdx.x;
  const int b0 = blockIdx.x * 8;
  const int sh = t >> 7;
  const int jq = t & 127;

  {
#pragma unroll
    for (int r = 0; r < 2; ++r) {
      const int i = t * 2 + r;  // 0..511
      const int k = i >> 3, s = i & 7;
      ((float*)&xs[s >> 2][k])[s & 3] = x[(size_t)(b0 + s) * 64 + k];
    }
    if (t < 128) mw[t] = 0;
  }
  __syncthreads();

  fwd_hidden(W1Tf, b1, xs[sh], hp[0][sh], mw, m1p + (size_t)b0 * 16, sh, jq, t, 64);
  fwd_hidden(W2Tf, b2, hp[0][sh], hp[1][sh], mw, m2p + (size_t)b0 * 16, sh, jq, t, 512);
  fwd_hidden(W3Tf, b3, hp[1][sh], hp[0][sh], mw, m3p + (size_t)b0 * 16, sh, jq, t, 512);

  // ---- layer 4 (K=512, D=64) + 0.5*||s||^2 : wave wv -> samples 2wv, 2wv+1 ----
  {
    const int wv = t >> 6, lane = t & 63;
    const int d = lane;
    const int s0 = wv * 2, s1 = s0 + 1;
    const float* h0 = (const float*)&hp[0][s0 >> 2][0] + (s0 & 3);
    const float* h1 = (const float*)&hp[0][s1 >> 2][0] + (s1 & 3);
    float acc0 = b4[d], acc1 = b4[d];
#pragma unroll 8
    for (int k = 0; k < 512; ++k) {
      const float w = W4Tf[k * 64 + d];
      acc0 = fmaf(w, h0[k * 4], acc0);
      acc1 = fmaf(w, h1[k * 4], acc1);
    }
    float sq0 = acc0 * acc0, sq1 = acc1 * acc1;
#pragma unroll
    for (int off = 32; off; off >>= 1) {
      sq0 += __shfl_down(sq0, off, 64);
      sq1 += __shfl_down(sq1, off, 64);
    }
    if (lane == 0) {
      out[b0 + s0] = 0.5f * sq0;
      out[b0 + s1] = 0.5f * sq1;
    }
  }
}

// ---------------- divergence: barrier-free dual bf16 MFMA stream ----------------
// grid (1024 sample-pairs, 4 row-tiles of 128); block 256 = 4 waves.
// wave (sLoc=wv&1, rh=wv>>1): sample g*2+sLoc, rows rowB0+rh*64..+64, cols 0..64.
// All operands loaded as pre-swizzled coalesced 1KB fragments; no LDS, no barriers.
__device__ __forceinline__ void expand_mask(uint32_t byte8, uint32_t mk[4]) {
#pragma unroll
  for (int i = 0; i < 4; ++i) {
    mk[i] = (((byte8 >> (2 * i)) & 1u) ? 0x0000FFFFu : 0u) |
            (((byte8 >> (2 * i + 1)) & 1u) ? 0xFFFF0000u : 0u);
  }
}

__global__ __launch_bounds__(256, 2) void div_kernel(
    const uint4* __restrict__ A2swz, const uint4* __restrict__ A3swz,
    const uint4* __restrict__ B1swz, const uint4* __restrict__ B4swz,
    const uint32_t* __restrict__ m1p, const uint32_t* __restrict__ m2p,
    const uint32_t* __restrict__ m3p, float* __restrict__ out) {
  const int t = threadIdx.x;
  const int lane = t & 63, wv = t >> 6;
  const int sLoc = wv & 1, rh = wv >> 1;
  const int l15 = lane & 15, quad = lane >> 4;
  const int g = blockIdx.x;
  const int rowB0 = blockIdx.y * 128;
  const int b = g * 2 + sLoc;
  const int r16b = (rowB0 >> 4) + rh * 4;

  f32x4 accC[4][4], accG[4][4];
#pragma unroll
  for (int it = 0; it < 4; ++it)
#pragma unroll
    for (int jt = 0; jt < 4; ++jt) {
      accC[it][jt] = (f32x4){0.f, 0.f, 0.f, 0.f};
      accG[it][jt] = (f32x4){0.f, 0.f, 0.f, 0.f};
    }

  const uint32_t* m1w = m1p + (size_t)b * 16;
  const uint32_t* m3w = m3p + (size_t)b * 16;

#pragma unroll 1
  for (int kc = 0; kc < 16; ++kc) {
    uint4 a2[4], u1[4], a3[4], u4[4];
    // C-group loads first, G-group second: compiler waits vmcnt(8) for C,
    // so C-MFMAs overlap the in-flight G loads.
#pragma unroll
    for (int it = 0; it < 4; ++it)
      a2[it] = A2swz[(size_t)((r16b + it) * 16 + kc) * 64 + lane];
#pragma unroll
    for (int jt = 0; jt < 4; ++jt)
      u1[jt] = B1swz[(size_t)(kc * 4 + jt) * 64 + lane];
#pragma unroll
    for (int it = 0; it < 4; ++it)
      a3[it] = A3swz[(size_t)((r16b + it) * 16 + kc) * 64 + lane];
#pragma unroll
    for (int jt = 0; jt < 4; ++jt)
      u4[jt] = B4swz[(size_t)(kc * 4 + jt) * 64 + lane];

    const uint32_t m1d = __builtin_amdgcn_readfirstlane(m1w[kc]);
    const uint32_t m3d = __builtin_amdgcn_readfirstlane(m3w[kc]);
    uint32_t mk1[4], mk3[4];
    expand_mask((m1d >> (quad * 8)) & 0xFFu, mk1);
    expand_mask((m3d >> (quad * 8)) & 0xFFu, mk3);

    short8 bC[4];
#pragma unroll
    for (int jt = 0; jt < 4; ++jt) {
      U16x8 u;
      u.u = u1[jt];
      u.u.x &= mk1[0]; u.u.y &= mk1[1]; u.u.z &= mk1[2]; u.u.w &= mk1[3];
      bC[jt] = u.s;
    }
#pragma unroll
    for (int it = 0; it < 4; ++it) {
      U16x8 ua;
      ua.u = a2[it];
      const short8 af = ua.s;
#pragma unroll
      for (int jt = 0; jt < 4; ++jt)
        accC[it][jt] = __builtin_amdgcn_mfma_f32_16x16x32_bf16(af, bC[jt], accC[it][jt], 0, 0, 0);
    }
    short8 bG[4];
#pragma unroll
    for (int jt = 0; jt < 4; ++jt) {
      U16x8 u;
      u.u = u4[jt];
      u.u.x &= mk3[0]; u.u.y &= mk3[1]; u.u.z &= mk3[2]; u.u.w &= mk3[3];
      bG[jt] = u.s;
    }
#pragma unroll
    for (int it = 0; it < 4; ++it) {
      U16x8 ua;
      ua.u = a3[it];
      const short8 af = ua.s;
#pragma unroll
      for (int jt = 0; jt < 4; ++jt)
        accG[it][jt] = __builtin_amdgcn_mfma_f32_16x16x32_bf16(af, bG[jt], accG[it][jt], 0, 0, 0);
    }
  }

  // epilogue: dsum = sum m2[row] * C .* G ; C/D layout: row = quad*4+reg, col = l15
  const uint32_t* m2w = m2p + (size_t)b * 16;
  float dsum = 0.f;
#pragma unroll
  for (int it = 0; it < 4; ++it) {
    const int rloc = rh * 64 + it * 16 + quad * 4;
    const uint32_t md = m2w[(rowB0 + rloc) >> 5];
    const uint32_t bits = (md >> (rloc & 31)) & 0xFu;
    const float w0 = (bits & 1u) ? 1.f : 0.f;
    const float w1 = (bits & 2u) ? 1.f : 0.f;
    const float w2 = (bits & 4u) ? 1.f : 0.f;
    const float w3 = (bits & 8u) ? 1.f : 0.f;
#pragma unroll
    for (int jt = 0; jt < 4; ++jt) {
      dsum = fmaf(w0, accC[it][jt][0] * accG[it][jt][0], dsum);
      dsum = fmaf(w1, accC[it][jt][1] * accG[it][jt][1], dsum);
      dsum = fmaf(w2, accC[it][jt][2] * accG[it][jt][2], dsum);
      dsum = fmaf(w3, accC[it][jt][3] * accG[it][jt][3], dsum);
    }
  }
#pragma unroll
  for (int off = 32; off; off >>= 1) dsum += __shfl_down(dsum, off, 64);
  if (lane == 0) atomicAdd(out + b, dsum);
}

extern "C" void kernel_launch(void* const* d_in, const int* in_sizes, int n_in,
                              void* d_out, int out_size, void* d_ws, size_t ws_size,
                              hipStream_t stream) {
  const float* x  = (const float*)d_in[0];
  const float* W1 = (const float*)d_in[1];
  const float* b1 = (const float*)d_in[2];
  const float* W2 = (const float*)d_in[3];
  const float* b2 = (const float*)d_in[4];
  const float* W3 = (const float*)d_in[5];
  const float* b3 = (const float*)d_in[6];
  const float* W4 = (const float*)d_in[7];
  const float* b4 = (const float*)d_in[8];
  float* out = (float*)d_out;

  // workspace layout (bytes), total 3,932,160:
  char* ws = (char*)d_ws;
  uint16_t* A2swz = (uint16_t*)(ws + 0);        // 524288
  uint16_t* A3swz = (uint16_t*)(ws + 524288);   // 524288
  uint16_t* B1swz = (uint16_t*)(ws + 1048576);  // 65536
  uint16_t* B4swz = (uint16_t*)(ws + 1114112);  // 65536
  float*    W2Tf  = (float*)(ws + 1179648);     // 1048576
  float*    W3Tf  = (float*)(ws + 2228224);     // 1048576
  float*    W1Tf  = (float*)(ws + 3276800);     // 131072
  float*    W4Tf  = (float*)(ws + 3407872);     // 131072
  uint32_t* m1p   = (uint32_t*)(ws + 3538944);  // 131072 (2048 x 512 bits)
  uint32_t* m2p   = (uint32_t*)(ws + 3670016);  // 131072
  uint32_t* m3p   = (uint32_t*)(ws + 3801088);  // 131072
  if (ws_size < 3932160) return;

  convert_kernel<<<4608, 256, 0, stream>>>(W1, W2, W3, W4,
                                           A2swz, A3swz, B1swz, B4swz,
                                           W2Tf, W3Tf, W1Tf, W4Tf);
  forward_kernel<<<256, 256, 0, stream>>>(x, W1Tf, b1, W2Tf, b2, W3Tf, b3,
                                          W4Tf, b4, m1p, m2p, m3p, out);
  div_kernel<<<dim3(1024, 4), 256, 0, stream>>>((const uint4*)A2swz,
                                                (const uint4*)A3swz,
                                                (const uint4*)B1swz,
                                                (const uint4*)B4swz,
                                                m1p, m2p, m3p, out);
}